// Round 7
// baseline (372.464 us; speedup 1.0000x reference)
//
#include <hip/hip_runtime.h>
#include <hip/hip_bf16.h>
#include <math.h>

#define H_DIM 2048
#define I_DIM 768
#define NEXP  8
#define TTOK  2048

typedef __bf16 bf16x8 __attribute__((ext_vector_type(8)));
typedef __bf16 bf16x4 __attribute__((ext_vector_type(4)));
typedef float  f32x4  __attribute__((ext_vector_type(4)));

// ---- workspace layout (bytes) ----
#define WS_COUNTS   0u
#define WS_TOK      128u          // NEXP*TTOK int    (65536)
#define WS_WGTW     65664u        // NEXP*TTOK float  (65536)
#define WS_XBF      131328u       // TTOK*H_DIM bf16  (8388608)
#define WS_HBUF     8519936u      // (4096+128)*I_DIM bf16 (6488064)
// no transposed-weight buffers anymore: GEMMs read native fp32 weights directly.

// async global->LDS, 16B per lane; LDS dest is wave-uniform base + lane*16,
// global source address is PER-LANE.
__device__ __forceinline__ void gl2l(const __bf16* g, __bf16* l) {
    __builtin_amdgcn_global_load_lds(
        (const __attribute__((address_space(1))) unsigned int*)g,
        (__attribute__((address_space(3))) unsigned int*)l, 16, 0, 0);
}
__device__ __forceinline__ void gl2lf(const float* g, float* l) {
    __builtin_amdgcn_global_load_lds(
        (const __attribute__((address_space(1))) unsigned int*)g,
        (__attribute__((address_space(3))) unsigned int*)l, 16, 0, 0);
}

// pipeline sync: wait until only N vector loads outstanding AND all LDS ops retired,
// then raw barrier (race fix: readers must retire before writers re-issue).
// encoding: vmcnt[3:0], expcnt[6:4]=7 (ignore), lgkmcnt[11:8]=0
__device__ __forceinline__ void pipe_sync_vm6() {
    asm volatile("" ::: "memory");
    __builtin_amdgcn_s_waitcnt(0x76);
    __builtin_amdgcn_s_barrier();
    asm volatile("" ::: "memory");
}
__device__ __forceinline__ void pipe_sync_vm0() {
    asm volatile("" ::: "memory");
    __builtin_amdgcn_s_waitcnt(0x70);
    __builtin_amdgcn_s_barrier();
    asm volatile("" ::: "memory");
}

// ---------------- router + x fp32->bf16 (the only prep left) ----------------
__global__ __launch_bounds__(256) void router_k(
    const float* __restrict__ x, const float* __restrict__ Wgate,
    int* __restrict__ counts, int* __restrict__ tok_list, float* __restrict__ wgt,
    __bf16* __restrict__ xb) {
    __shared__ float s_red[NEXP][4];
    __shared__ float s_logit[NEXP];
    const int tid = threadIdx.x;
    const int t = blockIdx.x;
    const float4* xr = (const float4*)(x + (size_t)t * H_DIM);
    bf16x4* xo = (bf16x4*)(xb + (size_t)t * H_DIM);
    float acc[NEXP];
#pragma unroll
    for (int e = 0; e < NEXP; ++e) acc[e] = 0.f;
#pragma unroll
    for (int j = 0; j < 2; ++j) {
        const int i4 = j * 256 + tid;                // 0..511 float4s
        float4 v = xr[i4];
        bf16x4 o;
        o[0] = (__bf16)v.x; o[1] = (__bf16)v.y; o[2] = (__bf16)v.z; o[3] = (__bf16)v.w;
        xo[i4] = o;
#pragma unroll
        for (int e = 0; e < NEXP; ++e) {
            float4 wv = *(const float4*)(Wgate + e * H_DIM + i4 * 4);
            acc[e] += v.x * wv.x + v.y * wv.y + v.z * wv.z + v.w * wv.w;
        }
    }
    const int lane = tid & 63, w = tid >> 6;
#pragma unroll
    for (int e = 0; e < NEXP; ++e) {
        float v = acc[e];
#pragma unroll
        for (int off = 32; off > 0; off >>= 1) v += __shfl_down(v, off, 64);
        if (lane == 0) s_red[e][w] = v;
    }
    __syncthreads();
    if (tid < NEXP) s_logit[tid] = s_red[tid][0] + s_red[tid][1] + s_red[tid][2] + s_red[tid][3];
    __syncthreads();
    if (tid == 0) {
        int i0 = 0; float l0 = s_logit[0];
        for (int e = 1; e < NEXP; ++e) if (s_logit[e] > l0) { l0 = s_logit[e]; i0 = e; }
        int i1 = -1; float l1 = -1e30f;
        for (int e = 0; e < NEXP; ++e) if (e != i0 && s_logit[e] > l1) { l1 = s_logit[e]; i1 = e; }
        float w0 = 1.f / (1.f + expf(l1 - l0));
        float w1 = 1.f - w0;
        int p0 = atomicAdd(&counts[i0], 1);
        tok_list[i0 * TTOK + p0] = t; wgt[i0 * TTOK + p0] = w0;
        int p1 = atomicAdd(&counts[i1], 1);
        tok_list[i1 * TTOK + p1] = t; wgt[i1 * TTOK + p1] = w1;
    }
}

// ---------------- GEMM1: h = silu(x@Wg)*(x@Wu); BM=128, BN=64(G)+64(U), BK=32 ------------
// Native fp32 weights staged via gl2l into LDS [32k][64n] fp32 tiles with wave-uniform
// column XOR ((w&1)*16); B-fragments gathered via 8x ds_read_b32 (read XOR (kq&1)*16:
// together a conflict-free 2-lanes/bank pattern) + RNE convert to bf16 in-register.
// 3-stage pipeline, 6 gl2l/wave/tile, vmcnt(6) steady + lgkm0 race drain.
__global__ __launch_bounds__(256, 2) void gemm1_k(
    const __bf16* __restrict__ xb, const float* __restrict__ Wg,
    const float* __restrict__ Wu, const int* __restrict__ counts,
    const int* __restrict__ tok_list, __bf16* __restrict__ hbuf) {
    const int g = blockIdx.x;
    const int e = g / 12, nt = g % 12;
    const int cnt = counts[e];
    const int m0 = blockIdx.y * 128;
    if (m0 >= cnt) return;
    const int tid = threadIdx.x;
    const int lane = tid & 63, w = tid >> 6;

    __shared__ __bf16 sA[3][128 * 32];   // bf16 A image (chunk-XOR slots), 24KB
    __shared__ float  sGf[3][32 * 64];   // fp32 G tiles, 24KB
    __shared__ float  sUf[3][32 * 64];   // fp32 U tiles, 24KB
    __shared__ int s_tok[128];
    __shared__ int s_off;

    if (tid == 0) { int o = 0; for (int j = 0; j < e; ++j) o += counts[j]; s_off = o; }
    if (tid < 128) {
        int m = m0 + tid;
        s_tok[tid] = tok_list[e * TTOK + (m < cnt ? m : cnt - 1)];
    }
    __syncthreads();
    const int off = s_off;

    // A staging: rows of 32 k-elems = 4 chunks of 16B; chunk c of row r at slot c^(r&3)
    const int srow = lane >> 2;                    // 0..15 within a 16-row group
    const int gof = ((lane & 3) ^ (srow & 3)) * 8; // logical chunk offset this lane stages
    const __bf16* pA[2]; int lofA[2];
#pragma unroll
    for (int i = 0; i < 2; ++i) {
        int r = i * 64 + w * 16 + srow;
        pA[i] = xb + (size_t)s_tok[r] * H_DIM + gof;
        lofA[i] = (i * 64 + w * 16) * 32;
    }
    // B staging (fp32 native): wave w stages rows w*8..w*8+7; per issue 4 rows x 64n.
    // lane covers row (lane>>4), cols (lane&15)*4 ^ ((w&1)*16)   [source XOR]
    const int bcol = ((lane & 15) * 4) ^ ((w & 1) * 16);
    const float* pGf = Wg + (size_t)e * H_DIM * I_DIM + (size_t)(w * 8 + (lane >> 4)) * I_DIM + nt * 64 + bcol;
    const float* pUf = Wu + (size_t)e * H_DIM * I_DIM + (size_t)(w * 8 + (lane >> 4)) * I_DIM + nt * 64 + bcol;
    const int lofB0 = (w * 8) * 64;      // fp32 offset of issue 0
    const int lofB1 = (w * 8 + 4) * 64;  // issue 1

    const int wm = w & 1, wn = w >> 1;
    const int l15 = lane & 15, kq = lane >> 4;
    const int swz = (kq ^ (l15 & 3)) * 8;          // A fragment k-chunk slot
    const int xw = (kq & 1) * 16;                  // B read-side XOR

    f32x4 accG[4][2], accU[4][2];
#pragma unroll
    for (int mf = 0; mf < 4; ++mf)
#pragma unroll
        for (int nf = 0; nf < 2; ++nf) {
            accG[mf][nf] = (f32x4){0.f, 0.f, 0.f, 0.f};
            accU[mf][nf] = (f32x4){0.f, 0.f, 0.f, 0.f};
        }

#define G1_ISSUE(T, BUF)                                                   \
    {                                                                      \
        const size_t ks_ = (size_t)(T) * 32 * I_DIM;                       \
        gl2l(pA[0] + (T) * 32, &sA[BUF][lofA[0]]);                         \
        gl2l(pA[1] + (T) * 32, &sA[BUF][lofA[1]]);                         \
        gl2lf(pGf + ks_,             &sGf[BUF][lofB0]);                    \
        gl2lf(pGf + ks_ + 4 * I_DIM, &sGf[BUF][lofB1]);                    \
        gl2lf(pUf + ks_,             &sUf[BUF][lofB0]);                    \
        gl2lf(pUf + ks_ + 4 * I_DIM, &sUf[BUF][lofB1]);                    \
    }

#define G1_COMPUTE(P)                                                                    \
    {                                                                                    \
        bf16x8 af[4], bg[2], bu[2];                                                      \
        _Pragma("unroll")                                                                \
        for (int mf = 0; mf < 4; ++mf)                                                   \
            af[mf] = *(const bf16x8*)(&sA[P][0] + (wm * 64 + mf * 16 + l15) * 32 + swz); \
        _Pragma("unroll")                                                                \
        for (int nf = 0; nf < 2; ++nf) {                                                 \
            const int nc_ = ((wn * 32 + nf * 16 + l15) ^ xw) + kq * 8 * 64;              \
            _Pragma("unroll")                                                            \
            for (int j = 0; j < 8; ++j) {                                                \
                bg[nf][j] = (__bf16)sGf[P][nc_ + j * 64];                                \
                bu[nf][j] = (__bf16)sUf[P][nc_ + j * 64];                                \
            }                                                                            \
        }                                                                                \
        _Pragma("unroll")                                                                \
        for (int mf = 0; mf < 4; ++mf)                                                   \
            _Pragma("unroll")                                                            \
            for (int nf = 0; nf < 2; ++nf) {                                             \
                accG[mf][nf] = __builtin_amdgcn_mfma_f32_16x16x32_bf16(af[mf], bg[nf], accG[mf][nf], 0, 0, 0); \
                accU[mf][nf] = __builtin_amdgcn_mfma_f32_16x16x32_bf16(af[mf], bu[nf], accU[mf][nf], 0, 0, 0); \
            }                                                                            \
    }

    // 64 k-tiles; 3-stage, depth-2 prefetch (12 loads in flight)
    G1_ISSUE(0, 0); G1_ISSUE(1, 1);
    int p = 0, q = 2;
    for (int it = 0; it < 62; ++it) {
        pipe_sync_vm6();                 // tile `it` landed; it+1 in flight
        G1_ISSUE(it + 2, q);
        G1_COMPUTE(p);
        p = (p == 2) ? 0 : p + 1;
        q = (q == 2) ? 0 : q + 1;
    }
    pipe_sync_vm6(); G1_COMPUTE(2);      // it=62  (62%3==2)
    pipe_sync_vm0(); G1_COMPUTE(0);      // it=63  (63%3==0)
#undef G1_ISSUE
#undef G1_COMPUTE

    // epilogue: silu(g)*u -> bf16 (C layout: col=lane&15, row=(lane>>4)*4+reg)
#pragma unroll
    for (int mf = 0; mf < 4; ++mf) {
#pragma unroll
        for (int reg = 0; reg < 4; ++reg) {
            int m = m0 + wm * 64 + mf * 16 + kq * 4 + reg;
            if (m < cnt) {
                size_t rowbase = (size_t)(off + m) * I_DIM;
#pragma unroll
                for (int nf = 0; nf < 2; ++nf) {
                    float g1 = accG[mf][nf][reg], u1 = accU[mf][nf][reg];
                    float h = (g1 / (1.f + __expf(-g1))) * u1;
                    hbuf[rowbase + nt * 64 + wn * 32 + nf * 16 + l15] = (__bf16)h;
                }
            }
        }
    }
}

// ---------------- GEMM2: y = h @ Wd, scatter-add w*y; BM=128, BN=128, BK=32 ----------------
// Native fp32 Wd [k=I][n=H] staged to LDS [32k][128n] fp32; same XOR scheme; same pipeline.
__global__ __launch_bounds__(256, 2) void gemm2_k(
    const __bf16* __restrict__ hbuf, const float* __restrict__ Wd,
    const int* __restrict__ counts, const int* __restrict__ tok_list,
    const float* __restrict__ wgt, float* __restrict__ out) {
    const int g = blockIdx.x;
    const int e = g >> 4, nt = g & 15;
    const int cnt = counts[e];
    const int m0 = blockIdx.y * 128;
    if (m0 >= cnt) return;
    const int tid = threadIdx.x;
    const int lane = tid & 63, w = tid >> 6;

    __shared__ __bf16 sA[3][128 * 32];   // 24KB
    __shared__ float  sBf[3][32 * 128];  // 48KB
    __shared__ int s_tok[128];
    __shared__ float s_w[128];
    __shared__ int s_off;

    if (tid == 0) { int o = 0; for (int j = 0; j < e; ++j) o += counts[j]; s_off = o; }
    if (tid < 128) {
        int m = m0 + tid;
        if (m < cnt) { s_tok[tid] = tok_list[e * TTOK + m]; s_w[tid] = wgt[e * TTOK + m]; }
        else         { s_tok[tid] = 0;                      s_w[tid] = 0.f; }
    }
    __syncthreads();
    const int off = s_off;

    const int srow = lane >> 2;
    const int gof = ((lane & 3) ^ (srow & 3)) * 8;
    const __bf16* pA[2]; int lofA[2];
#pragma unroll
    for (int i = 0; i < 2; ++i) {
        int r = i * 64 + w * 16 + srow;
        pA[i] = hbuf + (size_t)(off + m0 + r) * I_DIM + gof;
        lofA[i] = (i * 64 + w * 16) * 32;
    }
    // B staging: wave w stages rows w*8..+7; per issue 2 rows x 128n.
    // lane covers row (lane>>5), cols (lane&31)*4 ^ ((w&1)*16)
    const int bcol = ((lane & 31) * 4) ^ ((w & 1) * 16);
    const float* pBf = Wd + (size_t)e * I_DIM * H_DIM + (size_t)(w * 8 + (lane >> 5)) * H_DIM + nt * 128 + bcol;
    const int lofB = (w * 8) * 128;

    const int wm = w & 1, wn = w >> 1;
    const int l15 = lane & 15, kq = lane >> 4;
    const int swz = (kq ^ (l15 & 3)) * 8;
    const int xw = (kq & 1) * 16;

    f32x4 acc[4][4];
#pragma unroll
    for (int mf = 0; mf < 4; ++mf)
#pragma unroll
        for (int nf = 0; nf < 4; ++nf) acc[mf][nf] = (f32x4){0.f, 0.f, 0.f, 0.f};

#define G2_ISSUE(T, BUF)                                                   \
    {                                                                      \
        const size_t ks_ = (size_t)(T) * 32 * H_DIM;                       \
        gl2l(pA[0] + (T) * 32, &sA[BUF][lofA[0]]);                         \
        gl2l(pA[1] + (T) * 32, &sA[BUF][lofA[1]]);                         \
        gl2lf(pBf + ks_,             &sBf[BUF][lofB]);                     \
        gl2lf(pBf + ks_ + 2 * H_DIM, &sBf[BUF][lofB + 2 * 128]);           \
        gl2lf(pBf + ks_ + 4 * H_DIM, &sBf[BUF][lofB + 4 * 128]);           \
        gl2lf(pBf + ks_ + 6 * H_DIM, &sBf[BUF][lofB + 6 * 128]);           \
    }

#define G2_COMPUTE(P)                                                                    \
    {                                                                                    \
        bf16x8 af[4], bb[4];                                                             \
        _Pragma("unroll")                                                                \
        for (int mf = 0; mf < 4; ++mf)                                                   \
            af[mf] = *(const bf16x8*)(&sA[P][0] + (wm * 64 + mf * 16 + l15) * 32 + swz); \
        _Pragma("unroll")                                                                \
        for (int nf = 0; nf < 4; ++nf) {                                                 \
            const int nc_ = ((wn * 64 + nf * 16 + l15) ^ xw) + kq * 8 * 128;             \
            _Pragma("unroll")                                                            \
            for (int j = 0; j < 8; ++j) bb[nf][j] = (__bf16)sBf[P][nc_ + j * 128];       \
        }                                                                                \
        _Pragma("unroll")                                                                \
        for (int mf = 0; mf < 4; ++mf)                                                   \
            _Pragma("unroll")                                                            \
            for (int nf = 0; nf < 4; ++nf)                                               \
                acc[mf][nf] = __builtin_amdgcn_mfma_f32_16x16x32_bf16(af[mf], bb[nf], acc[mf][nf], 0, 0, 0); \
    }

    // 24 k-tiles; 3-stage, depth-2 prefetch
    G2_ISSUE(0, 0); G2_ISSUE(1, 1);
    int p = 0, q = 2;
    for (int it = 0; it < 22; ++it) {
        pipe_sync_vm6();
        G2_ISSUE(it + 2, q);
        G2_COMPUTE(p);
        p = (p == 2) ? 0 : p + 1;
        q = (q == 2) ? 0 : q + 1;
    }
    pipe_sync_vm6(); G2_COMPUTE(1);      // it=22  (22%3==1)
    pipe_sync_vm0(); G2_COMPUTE(2);      // it=23  (23%3==2)
#undef G2_ISSUE
#undef G2_COMPUTE

#pragma unroll
    for (int mf = 0; mf < 4; ++mf) {
#pragma unroll
        for (int reg = 0; reg < 4; ++reg) {
            int m_loc = wm * 64 + mf * 16 + kq * 4 + reg;
            if (m0 + m_loc < cnt) {
                int tok = s_tok[m_loc];
                float wv = s_w[m_loc];
                float* orow = out + (size_t)tok * H_DIM + nt * 128 + wn * 64 + l15;
#pragma unroll
                for (int nf = 0; nf < 4; ++nf)
                    atomicAdd(orow + nf * 16, wv * acc[mf][nf][reg]);
            }
        }
    }
}

extern "C" void kernel_launch(void* const* d_in, const int* in_sizes, int n_in,
                              void* d_out, int out_size, void* d_ws, size_t ws_size,
                              hipStream_t stream) {
    const float* x     = (const float*)d_in[0];
    const float* Wgate = (const float*)d_in[1];
    const float* Wg    = (const float*)d_in[2];
    const float* Wu    = (const float*)d_in[3];
    const float* Wd    = (const float*)d_in[4];
    float* out = (float*)d_out;
    char* ws = (char*)d_ws;

    int*    counts   = (int*)(ws + WS_COUNTS);
    int*    tok_list = (int*)(ws + WS_TOK);
    float*  wgt      = (float*)(ws + WS_WGTW);
    __bf16* xb       = (__bf16*)(ws + WS_XBF);
    __bf16* hbuf     = (__bf16*)(ws + WS_HBUF);

    hipMemsetAsync(counts, 0, 32, stream);
    hipMemsetAsync(d_out, 0, (size_t)TTOK * H_DIM * sizeof(float), stream);

    router_k<<<TTOK, 256, 0, stream>>>(x, Wgate, counts, tok_list, wgt, xb);
    gemm1_k<<<dim3(96, 16), 256, 0, stream>>>(xb, Wg, Wu, counts, tok_list, hbuf);
    gemm2_k<<<dim3(128, 16), 256, 0, stream>>>(hbuf, Wd, counts, tok_list, wgt, out);
}

// Round 8
// 334.996 us; speedup vs baseline: 1.1118x; 1.1118x over previous
//
#include <hip/hip_runtime.h>
#include <hip/hip_bf16.h>
#include <math.h>

#define H_DIM 2048
#define I_DIM 768
#define NEXP  8
#define TTOK  2048

typedef __bf16 bf16x8 __attribute__((ext_vector_type(8)));
typedef __bf16 bf16x4 __attribute__((ext_vector_type(4)));
typedef float  f32x4  __attribute__((ext_vector_type(4)));

// ---- workspace layout (bytes) ----
#define WS_COUNTS   0u
#define WS_TOK      128u          // NEXP*TTOK int    (65536)
#define WS_WGTW     65664u        // NEXP*TTOK float  (65536)
#define WS_XBF      131328u       // TTOK*H_DIM bf16  (8388608)
#define WS_HBUF     8519936u      // (4096+128)*I_DIM bf16 (6488064)
#define WS_WG_T     15008000u     // 8*12*64*2048 bf16 tiled (25165824)
#define WS_WU_T     40173824u     // same (25165824)
#define WS_WD_T     65339648u     // 8*16*24*4096 bf16 tiled (25165824)
// end: 90505472 (~86.3 MB)

// Tiled weight layouts (bf16), chunk-permuted to be the exact GEMM LDS image:
//  WgT/WuT: [e][nt=12][kt=64][64 rows][4 slots x 8], tile = 2048 elems (4KB)
//  WdT:     [e][nt=16][kt=24][128 rows][4 slots x 8], tile = 4096 elems (8KB)
//  slot s of row r holds logical k-chunk c = s ^ (r&3)  (8 consecutive k per chunk)

// async global->LDS, 16B per lane; LDS dest is wave-uniform base + lane*16
__device__ __forceinline__ void gl2l(const __bf16* g, __bf16* l) {
    __builtin_amdgcn_global_load_lds(
        (const __attribute__((address_space(1))) unsigned int*)g,
        (__attribute__((address_space(3))) unsigned int*)l, 16, 0, 0);
}

// pipeline sync: wait until only N vector loads outstanding AND all LDS ops retired,
// then raw barrier (race fix: readers must retire before writers re-issue).
// encoding: vmcnt[3:0], expcnt[6:4]=7 (ignore), lgkmcnt[11:8]=0
__device__ __forceinline__ void pipe_sync_vm8() {
    asm volatile("" ::: "memory");
    __builtin_amdgcn_s_waitcnt(0x78);
    __builtin_amdgcn_s_barrier();
    asm volatile("" ::: "memory");
}
__device__ __forceinline__ void pipe_sync_vm4() {
    asm volatile("" ::: "memory");
    __builtin_amdgcn_s_waitcnt(0x74);
    __builtin_amdgcn_s_barrier();
    asm volatile("" ::: "memory");
}
__device__ __forceinline__ void pipe_sync_vm0() {
    asm volatile("" ::: "memory");
    __builtin_amdgcn_s_waitcnt(0x70);
    __builtin_amdgcn_s_barrier();
    asm volatile("" ::: "memory");
}

// ---------------- prep v6: router + Wg/Wu transpose, REGISTER-HOISTED loads ----------------
// MLP fix: issue all global loads into registers FIRST (two separate loops), so the
// compiler emits back-to-back global_load_dwordx4 (~24KB in flight per wave) instead of
// throttling at 2-3 outstanding loads due to tight register reuse.
// grid (256-thr blocks):
//   [0, 1024)        : Wg/Wu transpose, block=(which,e,kt): reads 96KB contiguous,
//                      writes 12 dense 4KB tiles
//   [1024, 1024+2048): router for token t (also writes xb)
#define NBLK_A  1024
__global__ __launch_bounds__(256) void prep_k(
    const float* __restrict__ x, const float* __restrict__ Wgate,
    const float* __restrict__ Wg, const float* __restrict__ Wu,
    int* __restrict__ counts, int* __restrict__ tok_list, float* __restrict__ wgt,
    __bf16* __restrict__ xb, __bf16* __restrict__ Wg_t, __bf16* __restrict__ Wu_t) {
    __shared__ __bf16 sTb[32 * 772];   // [32 k][772 n-pad] bf16, 49408B
    __shared__ float s_red[NEXP][4];
    __shared__ float s_logit[NEXP];
    const int tid = threadIdx.x;
    const int b = blockIdx.x;

    if (b < NBLK_A) {
        // ---- Wg/Wu: rows k=kt*32..+32 (full 768 width, contiguous 96KB) ----
        const int which = b >> 9;
        const int e = (b >> 6) & 7;
        const int kt = b & 63;
        const float4* ip4 = (const float4*)((which ? Wu : Wg) + ((size_t)e * H_DIM + kt * 32) * I_DIM);
        // phase 1: issue ALL 24 loads (hoisted into registers)
        float4 v[24];
#pragma unroll
        for (int i = 0; i < 24; ++i) v[i] = ip4[i * 256 + tid];
        // phase 2: convert + LDS write
#pragma unroll
        for (int i = 0; i < 24; ++i) {
            const int f = i * 256 + tid;
            const int k = f / 192;
            const int n4 = (f - k * 192) * 4;
            bf16x4 o;
            o[0] = (__bf16)v[i].x; o[1] = (__bf16)v[i].y; o[2] = (__bf16)v[i].z; o[3] = (__bf16)v[i].w;
            *(bf16x4*)(&sTb[k * 772 + n4]) = o;
        }
        __syncthreads();
        __bf16* outp = which ? Wu_t : Wg_t;
#pragma unroll
        for (int i = 0; i < 3; ++i) {
            const int n = i * 256 + tid;          // 0..767 (output row / source col)
            const int nt = n >> 6, rn = n & 63;
            __bf16 col[32];
#pragma unroll
            for (int k = 0; k < 32; ++k) col[k] = sTb[k * 772 + n];
            __bf16* op = outp + ((size_t)((e * 12 + nt) * 64 + kt)) * 2048 + rn * 32;
            const int sw = rn & 3;
#pragma unroll
            for (int c = 0; c < 4; ++c) {
                bf16x8 o;
#pragma unroll
                for (int j = 0; j < 8; ++j) o[j] = col[c * 8 + j];
                *(bf16x8*)(op + ((c ^ sw) * 8)) = o;
            }
        }
        return;
    }

    // ---- router + x fp32->bf16 for token t (loads hoisted) ----
    const int t = b - NBLK_A;
    const float4* xr = (const float4*)(x + (size_t)t * H_DIM);
    bf16x4* xo = (bf16x4*)(xb + (size_t)t * H_DIM);
    float4 xv[2];
    float4 wv[2][NEXP];
#pragma unroll
    for (int j = 0; j < 2; ++j) {
        const int i4 = j * 256 + tid;
        xv[j] = xr[i4];
#pragma unroll
        for (int e = 0; e < NEXP; ++e)
            wv[j][e] = *(const float4*)(Wgate + e * H_DIM + i4 * 4);
    }
    float acc[NEXP];
#pragma unroll
    for (int e = 0; e < NEXP; ++e) acc[e] = 0.f;
#pragma unroll
    for (int j = 0; j < 2; ++j) {
        const int i4 = j * 256 + tid;
        float4 vx = xv[j];
        bf16x4 o;
        o[0] = (__bf16)vx.x; o[1] = (__bf16)vx.y; o[2] = (__bf16)vx.z; o[3] = (__bf16)vx.w;
        xo[i4] = o;
#pragma unroll
        for (int e = 0; e < NEXP; ++e) {
            acc[e] += vx.x * wv[j][e].x + vx.y * wv[j][e].y + vx.z * wv[j][e].z + vx.w * wv[j][e].w;
        }
    }
    const int lane = tid & 63, w = tid >> 6;
#pragma unroll
    for (int e = 0; e < NEXP; ++e) {
        float v = acc[e];
#pragma unroll
        for (int off = 32; off > 0; off >>= 1) v += __shfl_down(v, off, 64);
        if (lane == 0) s_red[e][w] = v;
    }
    __syncthreads();
    if (tid < NEXP) s_logit[tid] = s_red[tid][0] + s_red[tid][1] + s_red[tid][2] + s_red[tid][3];
    __syncthreads();
    if (tid == 0) {
        int i0 = 0; float l0 = s_logit[0];
        for (int e = 1; e < NEXP; ++e) if (s_logit[e] > l0) { l0 = s_logit[e]; i0 = e; }
        int i1 = -1; float l1 = -1e30f;
        for (int e = 0; e < NEXP; ++e) if (e != i0 && s_logit[e] > l1) { l1 = s_logit[e]; i1 = e; }
        float w0 = 1.f / (1.f + expf(l1 - l0));
        float w1 = 1.f - w0;
        int p0 = atomicAdd(&counts[i0], 1);
        tok_list[i0 * TTOK + p0] = t; wgt[i0 * TTOK + p0] = w0;
        int p1 = atomicAdd(&counts[i1], 1);
        tok_list[i1 * TTOK + p1] = t; wgt[i1 * TTOK + p1] = w1;
    }
}

// ---------------- GEMM1 (+ Wd-transpose backfill blocks) ----------------
// blocks [0,1536): h = silu(x@Wg)*(x@Wu); BM=128, BN=64(G)+64(U), BK=32.
// blocks [1536, 1536+768): Wd transpose tiles (register-hoisted loads) — independent
//   work that backfills CUs left idle by gemm1's vmcnt stalls / early-exit blocks.
__global__ __launch_bounds__(256, 2) void gemm1_k(
    const __bf16* __restrict__ xb, const __bf16* __restrict__ Wgt,
    const __bf16* __restrict__ Wut, const int* __restrict__ counts,
    const int* __restrict__ tok_list, __bf16* __restrict__ hbuf,
    const float* __restrict__ Wd, __bf16* __restrict__ Wd_t) {
    union SU {
        struct { __bf16 A[4][128 * 32]; __bf16 G[4][64 * 32]; __bf16 U[4][64 * 32]; } g; // 64KB
        __bf16 t[32 * 516];                                                              // 33KB
    };
    __shared__ SU sh;
    __shared__ int s_tok[128];
    __shared__ int s_off;
    const int lin = blockIdx.x;
    const int tid = threadIdx.x;

    if (lin >= 1536) {
        // ---- Wd transpose: rows k=kt*32..+32, cols q*512..+512 (hoisted loads) ----
        const int b2 = lin - 1536;
        const int e = b2 / 96;
        const int rem = b2 - e * 96;
        const int kt = rem >> 2, q = rem & 3;
        const float* ip = Wd + (size_t)e * I_DIM * H_DIM + (size_t)(kt * 32) * H_DIM + q * 512;
        float4 v[16];
#pragma unroll
        for (int i = 0; i < 16; ++i) {
            const int f = i * 256 + tid;          // 0..4095
            v[i] = *(const float4*)(ip + (size_t)(f >> 7) * H_DIM + (f & 127) * 4);
        }
#pragma unroll
        for (int i = 0; i < 16; ++i) {
            const int f = i * 256 + tid;
            const int k = f >> 7;
            const int n4 = (f & 127) * 4;
            bf16x4 o;
            o[0] = (__bf16)v[i].x; o[1] = (__bf16)v[i].y; o[2] = (__bf16)v[i].z; o[3] = (__bf16)v[i].w;
            *(bf16x4*)(&sh.t[k * 516 + n4]) = o;
        }
        __syncthreads();
#pragma unroll
        for (int i = 0; i < 2; ++i) {
            const int R = i * 256 + tid;          // 0..511 local col
            const int nt = q * 4 + (R >> 7), rn = R & 127;
            __bf16 col[32];
#pragma unroll
            for (int k = 0; k < 32; ++k) col[k] = sh.t[k * 516 + R];
            __bf16* op = Wd_t + ((size_t)((e * 16 + nt) * 24 + kt)) * 4096 + rn * 32;
            const int sw = rn & 3;
#pragma unroll
            for (int c = 0; c < 4; ++c) {
                bf16x8 o;
#pragma unroll
                for (int j = 0; j < 8; ++j) o[j] = col[c * 8 + j];
                *(bf16x8*)(op + ((c ^ sw) * 8)) = o;
            }
        }
        return;
    }

    const int g = lin % 96;
    const int e = g / 12, nt = g % 12;
    const int cnt = counts[e];
    const int m0 = (lin / 96) * 128;
    if (m0 >= cnt) return;
    const int lane = tid & 63, w = tid >> 6;

    if (tid == 0) { int o = 0; for (int j = 0; j < e; ++j) o += counts[j]; s_off = o; }
    if (tid < 128) {
        int m = m0 + tid;
        s_tok[tid] = tok_list[e * TTOK + (m < cnt ? m : cnt - 1)];
    }
    __syncthreads();
    const int off = s_off;

    // A staging: rows of 32 k-elems = 4 chunks of 16B; chunk c of row r at slot c^(r&3)
    const int srow = lane >> 2;                    // 0..15 within a 16-row group
    const int gof = ((lane & 3) ^ (srow & 3)) * 8; // logical chunk offset this lane stages
    const __bf16* pA[2]; int lofA[2];
#pragma unroll
    for (int i = 0; i < 2; ++i) {
        int r = i * 64 + w * 16 + srow;
        pA[i] = xb + (size_t)s_tok[r] * H_DIM + gof;
        lofA[i] = (i * 64 + w * 16) * 32;
    }
    // B staging: tiled layout, linear per wave
    const int lofGU = (w * 16) * 32;
    const __bf16* pG = Wgt + (size_t)(e * 12 + nt) * 64 * 2048 + w * 512 + lane * 8;
    const __bf16* pU = Wut + (size_t)(e * 12 + nt) * 64 * 2048 + w * 512 + lane * 8;

    const int wm = w & 1, wn = w >> 1;
    const int l15 = lane & 15, kq = lane >> 4;
    const int swz = (kq ^ (l15 & 3)) * 8;          // fragment k-chunk slot

    f32x4 accG[4][2], accU[4][2];
#pragma unroll
    for (int mf = 0; mf < 4; ++mf)
#pragma unroll
        for (int nf = 0; nf < 2; ++nf) {
            accG[mf][nf] = (f32x4){0.f, 0.f, 0.f, 0.f};
            accU[mf][nf] = (f32x4){0.f, 0.f, 0.f, 0.f};
        }

#define G1_ISSUE(T, BUF)                                             \
    {                                                                \
        gl2l(pA[0] + (T) * 32, &sh.g.A[BUF][lofA[0]]);               \
        gl2l(pA[1] + (T) * 32, &sh.g.A[BUF][lofA[1]]);               \
        gl2l(pG + (T) * 2048, &sh.g.G[BUF][lofGU]);                  \
        gl2l(pU + (T) * 2048, &sh.g.U[BUF][lofGU]);                  \
    }

#define G1_COMPUTE(P)                                                                      \
    {                                                                                      \
        bf16x8 af[4], bg[2], bu[2];                                                        \
        _Pragma("unroll")                                                                  \
        for (int mf = 0; mf < 4; ++mf)                                                     \
            af[mf] = *(const bf16x8*)(&sh.g.A[P][0] + (wm * 64 + mf * 16 + l15) * 32 + swz); \
        _Pragma("unroll")                                                                  \
        for (int nf = 0; nf < 2; ++nf) {                                                   \
            bg[nf] = *(const bf16x8*)(&sh.g.G[P][0] + (wn * 32 + nf * 16 + l15) * 32 + swz); \
            bu[nf] = *(const bf16x8*)(&sh.g.U[P][0] + (wn * 32 + nf * 16 + l15) * 32 + swz); \
        }                                                                                  \
        _Pragma("unroll")                                                                  \
        for (int mf = 0; mf < 4; ++mf)                                                     \
            _Pragma("unroll")                                                              \
            for (int nf = 0; nf < 2; ++nf) {                                               \
                accG[mf][nf] = __builtin_amdgcn_mfma_f32_16x16x32_bf16(af[mf], bg[nf], accG[mf][nf], 0, 0, 0); \
                accU[mf][nf] = __builtin_amdgcn_mfma_f32_16x16x32_bf16(af[mf], bu[nf], accU[mf][nf], 0, 0, 0); \
            }                                                                              \
    }

    // prefetch tiles 0,1,2 (12 loads/wave in flight)
    G1_ISSUE(0, 0); G1_ISSUE(1, 1); G1_ISSUE(2, 2);

    // steady: 64 tiles total; iters 0..59 issue tiles 3..62
#pragma unroll 4
    for (int it = 0; it < 60; ++it) {
        const int p = it & 3;
        pipe_sync_vm8();                 // tile `it` landed; it+1,it+2 in flight
        G1_ISSUE(it + 3, (it + 3) & 3);
        G1_COMPUTE(p);
    }
    pipe_sync_vm8(); G1_ISSUE(63, 3); G1_COMPUTE(0);   // it=60
    pipe_sync_vm8(); G1_COMPUTE(1);                    // it=61
    pipe_sync_vm4(); G1_COMPUTE(2);                    // it=62
    pipe_sync_vm0(); G1_COMPUTE(3);                    // it=63
#undef G1_ISSUE
#undef G1_COMPUTE

    // epilogue: silu(g)*u -> bf16 (C layout: col=lane&15, row=(lane>>4)*4+reg)
#pragma unroll
    for (int mf = 0; mf < 4; ++mf) {
#pragma unroll
        for (int reg = 0; reg < 4; ++reg) {
            int m = m0 + wm * 64 + mf * 16 + kq * 4 + reg;
            if (m < cnt) {
                size_t rowbase = (size_t)(off + m) * I_DIM;
#pragma unroll
                for (int nf = 0; nf < 2; ++nf) {
                    float g1 = accG[mf][nf][reg], u1 = accU[mf][nf][reg];
                    float h = (g1 / (1.f + __expf(-g1))) * u1;
                    hbuf[rowbase + nt * 64 + wn * 32 + nf * 16 + l15] = (__bf16)h;
                }
            }
        }
    }
}

// ---------------- GEMM2: y = h @ WdT, scatter-add w*y; BM=128, BN=128, BK=32 ----------------
// same pipeline; B-side reads tiled weights (8KB tiles, linear per wave).
__global__ __launch_bounds__(256, 2) void gemm2_k(
    const __bf16* __restrict__ hbuf, const __bf16* __restrict__ Wdt,
    const int* __restrict__ counts, const int* __restrict__ tok_list,
    const float* __restrict__ wgt, float* __restrict__ out) {
    const int g = blockIdx.x;
    const int e = g >> 4, nt = g & 15;
    const int cnt = counts[e];
    const int m0 = blockIdx.y * 128;
    if (m0 >= cnt) return;
    const int tid = threadIdx.x;
    const int lane = tid & 63, w = tid >> 6;

    __shared__ __bf16 sA[4][128 * 32];
    __shared__ __bf16 sB[4][128 * 32];
    __shared__ int s_tok[128];
    __shared__ float s_w[128];
    __shared__ int s_off;

    if (tid == 0) { int o = 0; for (int j = 0; j < e; ++j) o += counts[j]; s_off = o; }
    if (tid < 128) {
        int m = m0 + tid;
        if (m < cnt) { s_tok[tid] = tok_list[e * TTOK + m]; s_w[tid] = wgt[e * TTOK + m]; }
        else         { s_tok[tid] = 0;                      s_w[tid] = 0.f; }
    }
    __syncthreads();
    const int off = s_off;

    const int srow = lane >> 2;
    const int gof = ((lane & 3) ^ (srow & 3)) * 8;
    const __bf16* pA[2]; int lofA[2];
#pragma unroll
    for (int i = 0; i < 2; ++i) {
        int r = i * 64 + w * 16 + srow;
        pA[i] = hbuf + (size_t)(off + m0 + r) * I_DIM + gof;
        lofA[i] = (i * 64 + w * 16) * 32;
    }
    const int lofB0 = (w * 16) * 32;
    const int lofB1 = (64 + w * 16) * 32;
    const __bf16* pB0 = Wdt + (size_t)(e * 16 + nt) * 24 * 4096 + (w * 16) * 32 + lane * 8;
    const __bf16* pB1 = pB0 + 64 * 32;

    const int wm = w & 1, wn = w >> 1;
    const int l15 = lane & 15, kq = lane >> 4;
    const int swz = (kq ^ (l15 & 3)) * 8;

    f32x4 acc[4][4];
#pragma unroll
    for (int mf = 0; mf < 4; ++mf)
#pragma unroll
        for (int nf = 0; nf < 4; ++nf) acc[mf][nf] = (f32x4){0.f, 0.f, 0.f, 0.f};

#define G2_ISSUE(T, BUF)                                             \
    {                                                                \
        gl2l(pA[0] + (T) * 32, &sA[BUF][lofA[0]]);                   \
        gl2l(pA[1] + (T) * 32, &sA[BUF][lofA[1]]);                   \
        gl2l(pB0 + (T) * 4096, &sB[BUF][lofB0]);                     \
        gl2l(pB1 + (T) * 4096, &sB[BUF][lofB1]);                     \
    }

#define G2_COMPUTE(P)                                                                    \
    {                                                                                    \
        bf16x8 af[4], bb[4];                                                             \
        _Pragma("unroll")                                                                \
        for (int mf = 0; mf < 4; ++mf)                                                   \
            af[mf] = *(const bf16x8*)(&sA[P][0] + (wm * 64 + mf * 16 + l15) * 32 + swz); \
        _Pragma("unroll")                                                                \
        for (int nf = 0; nf < 4; ++nf)                                                   \
            bb[nf] = *(const bf16x8*)(&sB[P][0] + (wn * 64 + nf * 16 + l15) * 32 + swz); \
        _Pragma("unroll")                                                                \
        for (int mf = 0; mf < 4; ++mf)                                                   \
            _Pragma("unroll")                                                            \
            for (int nf = 0; nf < 4; ++nf)                                               \
                acc[mf][nf] = __builtin_amdgcn_mfma_f32_16x16x32_bf16(af[mf], bb[nf], acc[mf][nf], 0, 0, 0); \
    }

    // 24 tiles; prefetch 0,1,2; iters 0..19 issue tiles 3..22
    G2_ISSUE(0, 0); G2_ISSUE(1, 1); G2_ISSUE(2, 2);
#pragma unroll 4
    for (int it = 0; it < 20; ++it) {
        const int p = it & 3;
        pipe_sync_vm8();
        G2_ISSUE(it + 3, (it + 3) & 3);
        G2_COMPUTE(p);
    }
    pipe_sync_vm8(); G2_ISSUE(23, 3); G2_COMPUTE(0);   // it=20
    pipe_sync_vm8(); G2_COMPUTE(1);                    // it=21
    pipe_sync_vm4(); G2_COMPUTE(2);                    // it=22
    pipe_sync_vm0(); G2_COMPUTE(3);                    // it=23
#undef G2_ISSUE
#undef G2_COMPUTE

#pragma unroll
    for (int mf = 0; mf < 4; ++mf) {
#pragma unroll
        for (int reg = 0; reg < 4; ++reg) {
            int m_loc = wm * 64 + mf * 16 + kq * 4 + reg;
            if (m0 + m_loc < cnt) {
                int tok = s_tok[m_loc];
                float wv = s_w[m_loc];
                float* orow = out + (size_t)tok * H_DIM + nt * 128 + wn * 64 + l15;
#pragma unroll
                for (int nf = 0; nf < 4; ++nf)
                    atomicAdd(orow + nf * 16, wv * acc[mf][nf][reg]);
            }
        }
    }
}

extern "C" void kernel_launch(void* const* d_in, const int* in_sizes, int n_in,
                              void* d_out, int out_size, void* d_ws, size_t ws_size,
                              hipStream_t stream) {
    const float* x     = (const float*)d_in[0];
    const float* Wgate = (const float*)d_in[1];
    const float* Wg    = (const float*)d_in[2];
    const float* Wu    = (const float*)d_in[3];
    const float* Wd    = (const float*)d_in[4];
    float* out = (float*)d_out;
    char* ws = (char*)d_ws;

    int*    counts   = (int*)(ws + WS_COUNTS);
    int*    tok_list = (int*)(ws + WS_TOK);
    float*  wgt      = (float*)(ws + WS_WGTW);
    __bf16* xb       = (__bf16*)(ws + WS_XBF);
    __bf16* hbuf     = (__bf16*)(ws + WS_HBUF);
    __bf16* Wg_t     = (__bf16*)(ws + WS_WG_T);
    __bf16* Wu_t     = (__bf16*)(ws + WS_WU_T);
    __bf16* Wd_t     = (__bf16*)(ws + WS_WD_T);

    hipMemsetAsync(counts, 0, 32, stream);
    hipMemsetAsync(d_out, 0, (size_t)TTOK * H_DIM * sizeof(float), stream);

    // prep: Wg/Wu transpose [1024] + router [2048]  (Wd transpose rides in gemm1's grid)
    prep_k<<<NBLK_A + TTOK, 256, 0, stream>>>(x, Wgate, Wg, Wu,
                                              counts, tok_list, wgt, xb, Wg_t, Wu_t);
    // gemm1 blocks [0,1536) + Wd-transpose backfill blocks [1536,2304)
    gemm1_k<<<1536 + 768, 256, 0, stream>>>(xb, Wg_t, Wu_t, counts, tok_list, hbuf, Wd, Wd_t);
    gemm2_k<<<dim3(128, 16), 256, 0, stream>>>(hbuf, Wd_t, counts, tok_list, wgt, out);
}